// Round 1
// baseline (1035.319 us; speedup 1.0000x reference)
//
#include <hip/hip_runtime.h>
#include <cmath>

#define L_SEQ 4096
#define NH 8
#define DH 64
#define SS 45

// ---------------- QKV GEMM: (16384x512) @ (512x512), out in (bh,l,d) layout ----
__global__ __launch_bounds__(256) void qkv_gemm_kernel(
    const float* __restrict__ X,
    const float* __restrict__ Wq, const float* __restrict__ Wk, const float* __restrict__ Wv,
    float* __restrict__ Q, float* __restrict__ K, float* __restrict__ V)
{
    const float* W; float* Out;
    if (blockIdx.z == 0)      { W = Wq; Out = Q; }
    else if (blockIdx.z == 1) { W = Wk; Out = K; }
    else                      { W = Wv; Out = V; }

    __shared__ float As[16][132];
    __shared__ float Bs[16][132];

    int tid = threadIdx.x;
    int tx = tid & 15, ty = tid >> 4;
    int m0 = blockIdx.x * 128;
    int n0 = blockIdx.y * 128;

    int ar = tid >> 2;          // 0..63
    int ac = (tid & 3) << 2;    // 0,4,8,12
    int br = tid >> 5;          // 0..7
    int bc = (tid & 31) << 2;   // 0..124

    float acc[8][8];
    #pragma unroll
    for (int i = 0; i < 8; i++)
        #pragma unroll
        for (int j = 0; j < 8; j++) acc[i][j] = 0.f;

    for (int k0 = 0; k0 < 512; k0 += 16) {
        float4 a0 = *(const float4*)(X + (size_t)(m0 + ar) * 512 + k0 + ac);
        float4 a1 = *(const float4*)(X + (size_t)(m0 + ar + 64) * 512 + k0 + ac);
        float4 b0 = *(const float4*)(W + (size_t)(k0 + br) * 512 + n0 + bc);
        float4 b1 = *(const float4*)(W + (size_t)(k0 + br + 8) * 512 + n0 + bc);
        __syncthreads();
        As[ac + 0][ar] = a0.x; As[ac + 1][ar] = a0.y; As[ac + 2][ar] = a0.z; As[ac + 3][ar] = a0.w;
        As[ac + 0][ar + 64] = a1.x; As[ac + 1][ar + 64] = a1.y; As[ac + 2][ar + 64] = a1.z; As[ac + 3][ar + 64] = a1.w;
        *(float4*)&Bs[br][bc] = b0;
        *(float4*)&Bs[br + 8][bc] = b1;
        __syncthreads();
        #pragma unroll
        for (int kk = 0; kk < 16; kk++) {
            float4 aA = *(float4*)&As[kk][ty * 8];
            float4 aB = *(float4*)&As[kk][ty * 8 + 4];
            float4 bA = *(float4*)&Bs[kk][tx * 8];
            float4 bB = *(float4*)&Bs[kk][tx * 8 + 4];
            float a[8] = {aA.x, aA.y, aA.z, aA.w, aB.x, aB.y, aB.z, aB.w};
            float b[8] = {bA.x, bA.y, bA.z, bA.w, bB.x, bB.y, bB.z, bB.w};
            #pragma unroll
            for (int i = 0; i < 8; i++)
                #pragma unroll
                for (int j = 0; j < 8; j++) acc[i][j] += a[i] * b[j];
        }
    }
    // epilogue: row r -> (b = r>>12, l = r&4095); col c -> (h = c>>6, d = c&63)
    #pragma unroll
    for (int i = 0; i < 8; i++) {
        int r = m0 + ty * 8 + i;
        int b = r >> 12, l = r & 4095;
        int c0 = n0 + tx * 8;
        int h = c0 >> 6, d0 = c0 & 63;
        float* dst = Out + ((size_t)(b * 8 + h) * 4096 + l) * 64 + d0;
        *(float4*)dst       = make_float4(acc[i][0], acc[i][1], acc[i][2], acc[i][3]);
        *(float4*)(dst + 4) = make_float4(acc[i][4], acc[i][5], acc[i][6], acc[i][7]);
    }
}

// ---------------- M = max_s(q.k_samp) - mean_s(q.k_samp), fp32 ----------------
__global__ __launch_bounds__(256) void m_kernel(
    const float* __restrict__ Q, const float* __restrict__ K,
    const int* __restrict__ idx, float* __restrict__ M)
{
    int inst = blockIdx.x * 4 + (threadIdx.x >> 6);   // bh*4096 + l
    int lane = threadIdx.x & 63;
    int bh = inst >> 12;
    int l = inst & 4095;
    float qv = Q[(size_t)inst * 64 + lane];
    const float* kb = K + (size_t)bh * 4096 * 64;
    const int* irow = idx + (size_t)l * SS;
    float maxv = -1e30f, sum = 0.f;
    for (int s = 0; s < SS; s++) {
        int j = irow[s];
        float p = qv * kb[(size_t)j * 64 + lane];
        #pragma unroll
        for (int off = 32; off > 0; off >>= 1) p += __shfl_xor(p, off, 64);
        maxv = fmaxf(maxv, p);
        sum += p;
    }
    if (lane == 0) M[inst] = maxv - sum * (1.f / 45.f);
}

// ---------------- per-(b,h) top-45 of M over L ---------------------------------
__global__ __launch_bounds__(256) void topk_kernel(
    const float* __restrict__ M, int* __restrict__ tidx)
{
    int bh = blockIdx.x;
    __shared__ float vals[4096];
    __shared__ float rv[256];
    __shared__ int ri[256];
    int tid = threadIdx.x;
    for (int i = tid; i < 4096; i += 256) vals[i] = M[(size_t)bh * 4096 + i];
    __syncthreads();
    for (int it = 0; it < SS; it++) {
        float bv = -1e38f; int bi = 0;
        for (int i = tid; i < 4096; i += 256) {
            float v = vals[i];
            if (v > bv) { bv = v; bi = i; }
        }
        rv[tid] = bv; ri[tid] = bi;
        __syncthreads();
        for (int s = 128; s > 0; s >>= 1) {
            if (tid < s) {
                float v2 = rv[tid + s]; int i2 = ri[tid + s];
                if (v2 > rv[tid] || (v2 == rv[tid] && i2 < ri[tid])) { rv[tid] = v2; ri[tid] = i2; }
            }
            __syncthreads();
        }
        if (tid == 0) { tidx[bh * SS + it] = ri[0]; vals[ri[0]] = -1e38f; }
        __syncthreads();
    }
}

// ---------------- v mean partials over l-chunks --------------------------------
__global__ __launch_bounds__(256) void vmean_part_kernel(
    const float* __restrict__ V, float* __restrict__ vmp)
{
    int bh = blockIdx.x;       // 32
    int chunk = blockIdx.y;    // 16
    int d = threadIdx.x & 63, part = threadIdx.x >> 6;
    const float* vb = V + ((size_t)bh * 4096 + chunk * 256) * 64;
    float s = 0.f;
    for (int l = part; l < 256; l += 4) s += vb[(size_t)l * 64 + d];
    __shared__ float red[4][64];
    red[part][d] = s;
    __syncthreads();
    if (part == 0) vmp[((size_t)bh * 16 + chunk) * 64 + d] = red[0][d] + red[1][d] + red[2][d] + red[3][d];
}

// ---------------- vmean finalize + base_b = mean_row @ Wo ----------------------
__global__ __launch_bounds__(256) void base_kernel(
    const float* __restrict__ vmp, const float* __restrict__ Wo,
    float* __restrict__ vmean, float* __restrict__ base)
{
    int b = blockIdx.x;   // 4
    __shared__ float vmS[512];
    int tid = threadIdx.x;
    for (int i = tid; i < 512; i += 256) {
        int h = i >> 6, d = i & 63;
        float s = 0.f;
        #pragma unroll
        for (int c = 0; c < 16; c++) s += vmp[((size_t)(b * 8 + h) * 16 + c) * 64 + d];
        s *= (1.f / 4096.f);
        vmS[i] = s;
        vmean[(size_t)b * 512 + i] = s;    // laid out as [bh*64 + d]
    }
    __syncthreads();
    for (int j = tid; j < 512; j += 256) {
        float s = 0.f;
        for (int i = 0; i < 512; i++) s += vmS[i] * Wo[(size_t)i * 512 + j];
        base[(size_t)b * 512 + j] = s;
    }
}

// ---------------- scores = Qr . k * scale, per (bh, l-tile of 64) --------------
__global__ __launch_bounds__(256) void scores_kernel(
    const float* __restrict__ Q, const float* __restrict__ K,
    const int* __restrict__ tidx, float* __restrict__ attn)
{
    int ltile = blockIdx.x;   // 64
    int bh = blockIdx.y;      // 32
    __shared__ float Qs[48][68];
    __shared__ float Ks[64][68];
    __shared__ int tS[48];
    int tid = threadIdx.x;
    if (tid < 48) tS[tid] = (tid < SS) ? tidx[bh * SS + tid] : 0;
    __syncthreads();
    int lane = tid & 63, w = tid >> 6;
    for (int u = w; u < 48; u += 4)
        Qs[u][lane] = Q[((size_t)bh * 4096 + tS[u]) * 64 + lane];
    for (int r = w; r < 64; r += 4)
        Ks[r][lane] = K[((size_t)bh * 4096 + ltile * 64 + r) * 64 + lane];
    __syncthreads();
    if (tid < 192) {
        int ug = tid >> 4, lg = tid & 15;
        float acc[4][4];
        #pragma unroll
        for (int i = 0; i < 4; i++)
            #pragma unroll
            for (int j = 0; j < 4; j++) acc[i][j] = 0.f;
        for (int d0 = 0; d0 < 64; d0 += 4) {
            float4 a[4], b[4];
            #pragma unroll
            for (int i = 0; i < 4; i++) a[i] = *(float4*)&Qs[ug * 4 + i][d0];
            #pragma unroll
            for (int j = 0; j < 4; j++) b[j] = *(float4*)&Ks[lg * 4 + j][d0];
            #pragma unroll
            for (int i = 0; i < 4; i++)
                #pragma unroll
                for (int j = 0; j < 4; j++)
                    acc[i][j] += a[i].x * b[j].x + a[i].y * b[j].y + a[i].z * b[j].z + a[i].w * b[j].w;
        }
        const float scale = 0.125f;
        #pragma unroll
        for (int i = 0; i < 4; i++) {
            int u = ug * 4 + i;
            if (u < SS) {
                float4 r = make_float4(acc[i][0] * scale, acc[i][1] * scale,
                                       acc[i][2] * scale, acc[i][3] * scale);
                *(float4*)(attn + (size_t)(bh * SS + u) * 4096 + ltile * 64 + lg * 4) = r;
            }
        }
    }
}

// ---------------- softmax over L per (bh,u) row --------------------------------
__global__ __launch_bounds__(256) void softmax_kernel(float* __restrict__ attn)
{
    int rr = blockIdx.x;   // 1440
    float* row = attn + (size_t)rr * 4096;
    int tid = threadIdx.x;
    float v[16];
    float m = -1e30f;
    #pragma unroll
    for (int i = 0; i < 16; i++) { v[i] = row[tid + 256 * i]; m = fmaxf(m, v[i]); }
    __shared__ float red[256];
    red[tid] = m; __syncthreads();
    for (int s = 128; s > 0; s >>= 1) { if (tid < s) red[tid] = fmaxf(red[tid], red[tid + s]); __syncthreads(); }
    m = red[0]; __syncthreads();
    float sum = 0.f;
    #pragma unroll
    for (int i = 0; i < 16; i++) { v[i] = __expf(v[i] - m); sum += v[i]; }
    red[tid] = sum; __syncthreads();
    for (int s = 128; s > 0; s >>= 1) { if (tid < s) red[tid] += red[tid + s]; __syncthreads(); }
    float inv = 1.f / red[0];
    #pragma unroll
    for (int i = 0; i < 16; i++) row[tid + 256 * i] = v[i] * inv;
}

// ---------------- PV partials: ctx_partial[bh][ks][u][d] -----------------------
__global__ __launch_bounds__(256) void pv_kernel(
    const float* __restrict__ attn, const float* __restrict__ V,
    float* __restrict__ part)
{
    int bh = blockIdx.x;   // 32
    int ks = blockIdx.y;   // 16 chunks of 256 l
    int tid = threadIdx.x;
    int d = tid & 63, w = tid >> 6;
    float acc[12];
    #pragma unroll
    for (int j = 0; j < 12; j++) acc[j] = 0.f;
    const float* vb = V + ((size_t)bh * 4096 + ks * 256) * 64;
    for (int li = 0; li < 256; li++) {
        float vv = vb[(size_t)li * 64 + d];
        #pragma unroll
        for (int j = 0; j < 12; j++) {
            int u = w + 4 * j;
            float a = (u < SS) ? attn[(size_t)(bh * SS + u) * 4096 + ks * 256 + li] : 0.f;
            acc[j] += a * vv;
        }
    }
    #pragma unroll
    for (int j = 0; j < 12; j++) {
        int u = w + 4 * j;
        if (u < SS) part[(((size_t)bh * 16 + ks) * SS + u) * 64 + d] = acc[j];
    }
}

// ---------------- delta_out[bh,u,:] = (ctx_sel - vmean) @ Wo_h ------------------
__global__ __launch_bounds__(256) void delta_kernel(
    const float* __restrict__ part, const float* __restrict__ vmean,
    const float* __restrict__ Wo, float* __restrict__ dout)
{
    int rr = blockIdx.x;          // bh*45 + u
    int bh = rr / SS, u = rr % SS;
    int h = bh & 7;
    __shared__ float dS[64];
    int tid = threadIdx.x;
    if (tid < 64) {
        float s = 0.f;
        #pragma unroll
        for (int c = 0; c < 16; c++) s += part[(((size_t)bh * 16 + c) * SS + u) * 64 + tid];
        dS[tid] = s - vmean[(size_t)bh * 64 + tid];
    }
    __syncthreads();
    for (int j = tid; j < 512; j += 256) {
        float s = 0.f;
        #pragma unroll
        for (int dd = 0; dd < 64; dd++) s += dS[dd] * Wo[(size_t)(h * 64 + dd) * 512 + j];
        dout[(size_t)rr * 512 + j] = s;
    }
}

// ---------------- fill out with per-b base row ---------------------------------
__global__ __launch_bounds__(256) void fill_kernel(
    const float4* __restrict__ base4, float4* __restrict__ out4)
{
    int i = blockIdx.x * 256 + threadIdx.x;   // 0..2097151
    int b = i >> 19;
    int j4 = i & 127;
    out4[i] = base4[b * 128 + j4];
}

// ---------------- scatter-add deltas into selected rows -------------------------
__global__ __launch_bounds__(256) void scatter_kernel(
    const float* __restrict__ dout, const int* __restrict__ tidx,
    float* __restrict__ out)
{
    int rr = blockIdx.x;          // bh*45 + u
    int bh = rr / SS;
    int b = bh >> 3;
    int l = tidx[rr];
    float* orow = out + ((size_t)b * 4096 + l) * 512;
    const float* drow = dout + (size_t)rr * 512;
    for (int j = threadIdx.x; j < 512; j += 256)
        atomicAdd(orow + j, drow[j]);
}

extern "C" void kernel_launch(void* const* d_in, const int* in_sizes, int n_in,
                              void* d_out, int out_size, void* d_ws, size_t ws_size,
                              hipStream_t stream)
{
    const float* x  = (const float*)d_in[0];
    const float* Wq = (const float*)d_in[1];
    const float* Wk = (const float*)d_in[2];
    const float* Wv = (const float*)d_in[3];
    const float* Wo = (const float*)d_in[4];
    const int*  idx = (const int*)d_in[5];
    float* out = (float*)d_out;

    float* W = (float*)d_ws;
    float* Q     = W;                    // 8,388,608
    float* K     = W + 8388608;          // 8,388,608
    float* V     = W + 16777216;         // 8,388,608
    float* Mv    = W + 25165824;         // 131,072
    float* attn  = W + 25296896;         // 5,898,240
    float* part  = W + 31195136;         // 1,474,560
    float* dout  = W + 32669696;         // 737,280
    float* vmp   = W + 33406976;         // 32,768
    float* vmean = W + 33439744;         // 2,048
    float* base  = W + 33441792;         // 2,048
    int*   tidx  = (int*)(W + 33443840); // 1,440 ints
    // total ~133.8 MB of d_ws

    qkv_gemm_kernel<<<dim3(128, 4, 3), 256, 0, stream>>>(x, Wq, Wk, Wv, Q, K, V);
    m_kernel<<<32768, 256, 0, stream>>>(Q, K, idx, Mv);
    topk_kernel<<<32, 256, 0, stream>>>(Mv, tidx);
    vmean_part_kernel<<<dim3(32, 16), 256, 0, stream>>>(V, vmp);
    base_kernel<<<4, 256, 0, stream>>>(vmp, Wo, vmean, base);
    scores_kernel<<<dim3(64, 32), 256, 0, stream>>>(Q, K, tidx, attn);
    softmax_kernel<<<1440, 256, 0, stream>>>(attn);
    pv_kernel<<<dim3(32, 16), 256, 0, stream>>>(attn, V, part);
    delta_kernel<<<1440, 256, 0, stream>>>(part, vmean, Wo, dout);
    fill_kernel<<<8192, 256, 0, stream>>>((const float4*)base, (float4*)out);
    scatter_kernel<<<1440, 256, 0, stream>>>(dout, tidx, out);
}

// Round 2
// 767.792 us; speedup vs baseline: 1.3484x; 1.3484x over previous
//
#include <hip/hip_runtime.h>
#include <cmath>

#define L_SEQ 4096
#define NH 8
#define DH 64
#define SS 45

// ---------------- QKV GEMM: (16384x512) @ (512x512), out in (bh,l,d) layout ----
__global__ __launch_bounds__(256) void qkv_gemm_kernel(
    const float* __restrict__ X,
    const float* __restrict__ Wq, const float* __restrict__ Wk, const float* __restrict__ Wv,
    float* __restrict__ Q, float* __restrict__ K, float* __restrict__ V)
{
    const float* W; float* Out;
    if (blockIdx.z == 0)      { W = Wq; Out = Q; }
    else if (blockIdx.z == 1) { W = Wk; Out = K; }
    else                      { W = Wv; Out = V; }

    __shared__ float As[16][132];
    __shared__ float Bs[16][132];

    int tid = threadIdx.x;
    int tx = tid & 15, ty = tid >> 4;
    int m0 = blockIdx.x * 128;
    int n0 = blockIdx.y * 128;

    int ar = tid >> 2;          // 0..63
    int ac = (tid & 3) << 2;    // 0,4,8,12
    int br = tid >> 5;          // 0..7
    int bc = (tid & 31) << 2;   // 0..124

    float acc[8][8];
    #pragma unroll
    for (int i = 0; i < 8; i++)
        #pragma unroll
        for (int j = 0; j < 8; j++) acc[i][j] = 0.f;

    for (int k0 = 0; k0 < 512; k0 += 16) {
        float4 a0 = *(const float4*)(X + (size_t)(m0 + ar) * 512 + k0 + ac);
        float4 a1 = *(const float4*)(X + (size_t)(m0 + ar + 64) * 512 + k0 + ac);
        float4 b0 = *(const float4*)(W + (size_t)(k0 + br) * 512 + n0 + bc);
        float4 b1 = *(const float4*)(W + (size_t)(k0 + br + 8) * 512 + n0 + bc);
        __syncthreads();
        As[ac + 0][ar] = a0.x; As[ac + 1][ar] = a0.y; As[ac + 2][ar] = a0.z; As[ac + 3][ar] = a0.w;
        As[ac + 0][ar + 64] = a1.x; As[ac + 1][ar + 64] = a1.y; As[ac + 2][ar + 64] = a1.z; As[ac + 3][ar + 64] = a1.w;
        *(float4*)&Bs[br][bc] = b0;
        *(float4*)&Bs[br + 8][bc] = b1;
        __syncthreads();
        #pragma unroll
        for (int kk = 0; kk < 16; kk++) {
            float4 aA = *(float4*)&As[kk][ty * 8];
            float4 aB = *(float4*)&As[kk][ty * 8 + 4];
            float4 bA = *(float4*)&Bs[kk][tx * 8];
            float4 bB = *(float4*)&Bs[kk][tx * 8 + 4];
            float a[8] = {aA.x, aA.y, aA.z, aA.w, aB.x, aB.y, aB.z, aB.w};
            float b[8] = {bA.x, bA.y, bA.z, bA.w, bB.x, bB.y, bB.z, bB.w};
            #pragma unroll
            for (int i = 0; i < 8; i++)
                #pragma unroll
                for (int j = 0; j < 8; j++) acc[i][j] += a[i] * b[j];
        }
    }
    // epilogue: row r -> (b = r>>12, l = r&4095); col c -> (h = c>>6, d = c&63)
    #pragma unroll
    for (int i = 0; i < 8; i++) {
        int r = m0 + ty * 8 + i;
        int b = r >> 12, l = r & 4095;
        int c0 = n0 + tx * 8;
        int h = c0 >> 6, d0 = c0 & 63;
        float* dst = Out + ((size_t)(b * 8 + h) * 4096 + l) * 64 + d0;
        *(float4*)dst       = make_float4(acc[i][0], acc[i][1], acc[i][2], acc[i][3]);
        *(float4*)(dst + 4) = make_float4(acc[i][4], acc[i][5], acc[i][6], acc[i][7]);
    }
}

// ---------------- M = max_s(q.k_samp) - mean_s(q.k_samp), fp32 ----------------
// Wave = one (bh,l). 4 lane-groups of 16; group g owns sample s = 4*it + g.
// Lane t in group holds q/k d-slice [t*4, t*4+4). Intra-group 4-step butterfly
// (independent across groups), then 2-step cross-group combine.
__global__ __launch_bounds__(256) void m_kernel(
    const float* __restrict__ Q, const float* __restrict__ K,
    const int* __restrict__ idx, float* __restrict__ M)
{
    int inst = blockIdx.x * 4 + (threadIdx.x >> 6);   // bh*4096 + l
    int lane = threadIdx.x & 63;
    int g = lane >> 4;        // group 0..3
    int t = lane & 15;        // lane in group
    int bh = inst >> 12;
    int l = inst & 4095;
    float4 qv = *(const float4*)(Q + (size_t)inst * 64 + t * 4);
    const float* kb = K + (size_t)bh * 4096 * 64;
    const int* irow = idx + (size_t)l * SS;
    float maxv = -1e30f, sum = 0.f;
    #pragma unroll
    for (int it = 0; it < 12; it++) {
        int s = it * 4 + g;
        bool valid = (s < SS);
        int j = irow[valid ? s : 0];
        float4 kv = *(const float4*)(kb + (size_t)j * 64 + t * 4);
        float p = qv.x * kv.x + qv.y * kv.y + qv.z * kv.z + qv.w * kv.w;
        p += __shfl_xor(p, 1, 64);
        p += __shfl_xor(p, 2, 64);
        p += __shfl_xor(p, 4, 64);
        p += __shfl_xor(p, 8, 64);
        if (valid) { maxv = fmaxf(maxv, p); sum += p; }
    }
    maxv = fmaxf(maxv, __shfl_xor(maxv, 16, 64));
    maxv = fmaxf(maxv, __shfl_xor(maxv, 32, 64));
    sum += __shfl_xor(sum, 16, 64);
    sum += __shfl_xor(sum, 32, 64);
    if (lane == 0) M[inst] = maxv - sum * (1.f / 45.f);
}

// ---------------- per-(b,h) top-45 of M over L ---------------------------------
__global__ __launch_bounds__(256) void topk_kernel(
    const float* __restrict__ M, int* __restrict__ tidx)
{
    int bh = blockIdx.x;
    __shared__ float vals[4096];
    __shared__ float rv[256];
    __shared__ int ri[256];
    int tid = threadIdx.x;
    for (int i = tid; i < 4096; i += 256) vals[i] = M[(size_t)bh * 4096 + i];
    __syncthreads();
    for (int it = 0; it < SS; it++) {
        float bv = -1e38f; int bi = 0;
        for (int i = tid; i < 4096; i += 256) {
            float v = vals[i];
            if (v > bv) { bv = v; bi = i; }
        }
        rv[tid] = bv; ri[tid] = bi;
        __syncthreads();
        for (int s = 128; s > 0; s >>= 1) {
            if (tid < s) {
                float v2 = rv[tid + s]; int i2 = ri[tid + s];
                if (v2 > rv[tid] || (v2 == rv[tid] && i2 < ri[tid])) { rv[tid] = v2; ri[tid] = i2; }
            }
            __syncthreads();
        }
        if (tid == 0) { tidx[bh * SS + it] = ri[0]; vals[ri[0]] = -1e38f; }
        __syncthreads();
    }
}

// ---------------- v mean partials over l-chunks --------------------------------
__global__ __launch_bounds__(256) void vmean_part_kernel(
    const float* __restrict__ V, float* __restrict__ vmp)
{
    int bh = blockIdx.x;       // 32
    int chunk = blockIdx.y;    // 16
    int d = threadIdx.x & 63, part = threadIdx.x >> 6;
    const float* vb = V + ((size_t)bh * 4096 + chunk * 256) * 64;
    float s = 0.f;
    for (int l = part; l < 256; l += 4) s += vb[(size_t)l * 64 + d];
    __shared__ float red[4][64];
    red[part][d] = s;
    __syncthreads();
    if (part == 0) vmp[((size_t)bh * 16 + chunk) * 64 + d] = red[0][d] + red[1][d] + red[2][d] + red[3][d];
}

// ---------------- vmean finalize + base_b = mean_row @ Wo ----------------------
__global__ __launch_bounds__(256) void base_kernel(
    const float* __restrict__ vmp, const float* __restrict__ Wo,
    float* __restrict__ vmean, float* __restrict__ base)
{
    int b = blockIdx.x;   // 4
    __shared__ float vmS[512];
    int tid = threadIdx.x;
    for (int i = tid; i < 512; i += 256) {
        int h = i >> 6, d = i & 63;
        float s = 0.f;
        #pragma unroll
        for (int c = 0; c < 16; c++) s += vmp[((size_t)(b * 8 + h) * 16 + c) * 64 + d];
        s *= (1.f / 4096.f);
        vmS[i] = s;
        vmean[(size_t)b * 512 + i] = s;    // laid out as [bh*64 + d]
    }
    __syncthreads();
    for (int j = tid; j < 512; j += 256) {
        float s = 0.f;
        for (int i = 0; i < 512; i++) s += vmS[i] * Wo[(size_t)i * 512 + j];
        base[(size_t)b * 512 + j] = s;
    }
}

// ---------------- scores = Qr . k * scale, per (bh, l-tile of 64) --------------
__global__ __launch_bounds__(256) void scores_kernel(
    const float* __restrict__ Q, const float* __restrict__ K,
    const int* __restrict__ tidx, float* __restrict__ attn)
{
    int ltile = blockIdx.x;   // 64
    int bh = blockIdx.y;      // 32
    __shared__ float Qs[48][68];
    __shared__ float Ks[64][68];
    __shared__ int tS[48];
    int tid = threadIdx.x;
    if (tid < 48) tS[tid] = (tid < SS) ? tidx[bh * SS + tid] : 0;
    __syncthreads();
    int lane = tid & 63, w = tid >> 6;
    for (int u = w; u < 48; u += 4)
        Qs[u][lane] = Q[((size_t)bh * 4096 + tS[u]) * 64 + lane];
    for (int r = w; r < 64; r += 4)
        Ks[r][lane] = K[((size_t)bh * 4096 + ltile * 64 + r) * 64 + lane];
    __syncthreads();
    if (tid < 192) {
        int ug = tid >> 4, lg = tid & 15;
        float acc[4][4];
        #pragma unroll
        for (int i = 0; i < 4; i++)
            #pragma unroll
            for (int j = 0; j < 4; j++) acc[i][j] = 0.f;
        for (int d0 = 0; d0 < 64; d0 += 4) {
            float4 a[4], b[4];
            #pragma unroll
            for (int i = 0; i < 4; i++) a[i] = *(float4*)&Qs[ug * 4 + i][d0];
            #pragma unroll
            for (int j = 0; j < 4; j++) b[j] = *(float4*)&Ks[lg * 4 + j][d0];
            #pragma unroll
            for (int i = 0; i < 4; i++)
                #pragma unroll
                for (int j = 0; j < 4; j++)
                    acc[i][j] += a[i].x * b[j].x + a[i].y * b[j].y + a[i].z * b[j].z + a[i].w * b[j].w;
        }
        const float scale = 0.125f;
        #pragma unroll
        for (int i = 0; i < 4; i++) {
            int u = ug * 4 + i;
            if (u < SS) {
                float4 r = make_float4(acc[i][0] * scale, acc[i][1] * scale,
                                       acc[i][2] * scale, acc[i][3] * scale);
                *(float4*)(attn + (size_t)(bh * SS + u) * 4096 + ltile * 64 + lg * 4) = r;
            }
        }
    }
}

// ---------------- softmax over L per (bh,u) row --------------------------------
__global__ __launch_bounds__(256) void softmax_kernel(float* __restrict__ attn)
{
    int rr = blockIdx.x;   // 1440
    float* row = attn + (size_t)rr * 4096;
    int tid = threadIdx.x;
    float v[16];
    float m = -1e30f;
    #pragma unroll
    for (int i = 0; i < 16; i++) { v[i] = row[tid + 256 * i]; m = fmaxf(m, v[i]); }
    __shared__ float red[256];
    red[tid] = m; __syncthreads();
    for (int s = 128; s > 0; s >>= 1) { if (tid < s) red[tid] = fmaxf(red[tid], red[tid + s]); __syncthreads(); }
    m = red[0]; __syncthreads();
    float sum = 0.f;
    #pragma unroll
    for (int i = 0; i < 16; i++) { v[i] = __expf(v[i] - m); sum += v[i]; }
    red[tid] = sum; __syncthreads();
    for (int s = 128; s > 0; s >>= 1) { if (tid < s) red[tid] += red[tid + s]; __syncthreads(); }
    float inv = 1.f / red[0];
    #pragma unroll
    for (int i = 0; i < 16; i++) row[tid + 256 * i] = v[i] * inv;
}

// ---------------- PV partials: ctx_partial[bh][ks][u][d] -----------------------
__global__ __launch_bounds__(256) void pv_kernel(
    const float* __restrict__ attn, const float* __restrict__ V,
    float* __restrict__ part)
{
    int bh = blockIdx.x;   // 32
    int ks = blockIdx.y;   // 16 chunks of 256 l
    int tid = threadIdx.x;
    int d = tid & 63, w = tid >> 6;
    float acc[12];
    #pragma unroll
    for (int j = 0; j < 12; j++) acc[j] = 0.f;
    const float* vb = V + ((size_t)bh * 4096 + ks * 256) * 64;
    for (int li = 0; li < 256; li++) {
        float vv = vb[(size_t)li * 64 + d];
        #pragma unroll
        for (int j = 0; j < 12; j++) {
            int u = w + 4 * j;
            float a = (u < SS) ? attn[(size_t)(bh * SS + u) * 4096 + ks * 256 + li] : 0.f;
            acc[j] += a * vv;
        }
    }
    #pragma unroll
    for (int j = 0; j < 12; j++) {
        int u = w + 4 * j;
        if (u < SS) part[(((size_t)bh * 16 + ks) * SS + u) * 64 + d] = acc[j];
    }
}

// ---------------- delta_out[bh,u,:] = (ctx_sel - vmean) @ Wo_h ------------------
__global__ __launch_bounds__(256) void delta_kernel(
    const float* __restrict__ part, const float* __restrict__ vmean,
    const float* __restrict__ Wo, float* __restrict__ dout)
{
    int rr = blockIdx.x;          // bh*45 + u
    int bh = rr / SS, u = rr % SS;
    int h = bh & 7;
    __shared__ float dS[64];
    int tid = threadIdx.x;
    if (tid < 64) {
        float s = 0.f;
        #pragma unroll
        for (int c = 0; c < 16; c++) s += part[(((size_t)bh * 16 + c) * SS + u) * 64 + tid];
        dS[tid] = s - vmean[(size_t)bh * 64 + tid];
    }
    __syncthreads();
    for (int j = tid; j < 512; j += 256) {
        float s = 0.f;
        #pragma unroll
        for (int dd = 0; dd < 64; dd++) s += dS[dd] * Wo[(size_t)(h * 64 + dd) * 512 + j];
        dout[(size_t)rr * 512 + j] = s;
    }
}

// ---------------- fill out with per-b base row ---------------------------------
__global__ __launch_bounds__(256) void fill_kernel(
    const float4* __restrict__ base4, float4* __restrict__ out4)
{
    int i = blockIdx.x * 256 + threadIdx.x;   // 0..2097151
    int b = i >> 19;
    int j4 = i & 127;
    out4[i] = base4[b * 128 + j4];
}

// ---------------- scatter-add deltas into selected rows -------------------------
__global__ __launch_bounds__(256) void scatter_kernel(
    const float* __restrict__ dout, const int* __restrict__ tidx,
    float* __restrict__ out)
{
    int rr = blockIdx.x;          // bh*45 + u
    int bh = rr / SS;
    int b = bh >> 3;
    int l = tidx[rr];
    float* orow = out + ((size_t)b * 4096 + l) * 512;
    const float* drow = dout + (size_t)rr * 512;
    for (int j = threadIdx.x; j < 512; j += 256)
        atomicAdd(orow + j, drow[j]);
}

extern "C" void kernel_launch(void* const* d_in, const int* in_sizes, int n_in,
                              void* d_out, int out_size, void* d_ws, size_t ws_size,
                              hipStream_t stream)
{
    const float* x  = (const float*)d_in[0];
    const float* Wq = (const float*)d_in[1];
    const float* Wk = (const float*)d_in[2];
    const float* Wv = (const float*)d_in[3];
    const float* Wo = (const float*)d_in[4];
    const int*  idx = (const int*)d_in[5];
    float* out = (float*)d_out;

    float* W = (float*)d_ws;
    float* Q     = W;                    // 8,388,608
    float* K     = W + 8388608;          // 8,388,608
    float* V     = W + 16777216;         // 8,388,608
    float* Mv    = W + 25165824;         // 131,072
    float* attn  = W + 25296896;         // 5,898,240
    float* part  = W + 31195136;         // 1,474,560
    float* dout  = W + 32669696;         // 737,280
    float* vmp   = W + 33406976;         // 32,768
    float* vmean = W + 33439744;         // 2,048
    float* base  = W + 33441792;         // 2,048
    int*   tidx  = (int*)(W + 33443840); // 1,440 ints
    // total ~133.8 MB of d_ws

    qkv_gemm_kernel<<<dim3(128, 4, 3), 256, 0, stream>>>(x, Wq, Wk, Wv, Q, K, V);
    m_kernel<<<32768, 256, 0, stream>>>(Q, K, idx, Mv);
    topk_kernel<<<32, 256, 0, stream>>>(Mv, tidx);
    vmean_part_kernel<<<dim3(32, 16), 256, 0, stream>>>(V, vmp);
    base_kernel<<<4, 256, 0, stream>>>(vmp, Wo, vmean, base);
    scores_kernel<<<dim3(64, 32), 256, 0, stream>>>(Q, K, tidx, attn);
    softmax_kernel<<<1440, 256, 0, stream>>>(attn);
    pv_kernel<<<dim3(32, 16), 256, 0, stream>>>(attn, V, part);
    delta_kernel<<<1440, 256, 0, stream>>>(part, vmean, Wo, dout);
    fill_kernel<<<8192, 256, 0, stream>>>((const float4*)base, (float4*)out);
    scatter_kernel<<<1440, 256, 0, stream>>>(dout, tidx, out);
}

// Round 3
// 700.787 us; speedup vs baseline: 1.4774x; 1.0956x over previous
//
#include <hip/hip_runtime.h>
#include <cmath>

#define L_SEQ 4096
#define NH 8
#define DH 64
#define SS 45

typedef __attribute__((ext_vector_type(8))) short short8;
typedef __attribute__((ext_vector_type(4))) float float4v;

__device__ inline unsigned short bf16r(float f) {
    unsigned int u = __float_as_uint(f);
    unsigned int r = (u + 0x7fff + ((u >> 16) & 1)) >> 16;
    return (unsigned short)r;
}

// ---------------- Q/K GEMM (fp32, selection-critical): (16384x512)@(512x512) ---
__global__ __launch_bounds__(256) void qk_gemm_kernel(
    const float* __restrict__ X,
    const float* __restrict__ Wq, const float* __restrict__ Wk,
    float* __restrict__ Q, float* __restrict__ K)
{
    const float* W; float* Out;
    if (blockIdx.z == 0) { W = Wq; Out = Q; }
    else                 { W = Wk; Out = K; }

    __shared__ float As[16][132];
    __shared__ float Bs[16][132];

    int tid = threadIdx.x;
    int tx = tid & 15, ty = tid >> 4;
    int m0 = blockIdx.x * 128;
    int n0 = blockIdx.y * 128;

    int ar = tid >> 2;          // 0..63
    int ac = (tid & 3) << 2;    // 0,4,8,12
    int br = tid >> 5;          // 0..7
    int bc = (tid & 31) << 2;   // 0..124

    float acc[8][8];
    #pragma unroll
    for (int i = 0; i < 8; i++)
        #pragma unroll
        for (int j = 0; j < 8; j++) acc[i][j] = 0.f;

    for (int k0 = 0; k0 < 512; k0 += 16) {
        float4 a0 = *(const float4*)(X + (size_t)(m0 + ar) * 512 + k0 + ac);
        float4 a1 = *(const float4*)(X + (size_t)(m0 + ar + 64) * 512 + k0 + ac);
        float4 b0 = *(const float4*)(W + (size_t)(k0 + br) * 512 + n0 + bc);
        float4 b1 = *(const float4*)(W + (size_t)(k0 + br + 8) * 512 + n0 + bc);
        __syncthreads();
        As[ac + 0][ar] = a0.x; As[ac + 1][ar] = a0.y; As[ac + 2][ar] = a0.z; As[ac + 3][ar] = a0.w;
        As[ac + 0][ar + 64] = a1.x; As[ac + 1][ar + 64] = a1.y; As[ac + 2][ar + 64] = a1.z; As[ac + 3][ar + 64] = a1.w;
        *(float4*)&Bs[br][bc] = b0;
        *(float4*)&Bs[br + 8][bc] = b1;
        __syncthreads();
        #pragma unroll
        for (int kk = 0; kk < 16; kk++) {
            float4 aA = *(float4*)&As[kk][ty * 8];
            float4 aB = *(float4*)&As[kk][ty * 8 + 4];
            // bank-conflict-free B fragment: cols {tx*4..+3} and {64+tx*4..+3}
            float4 bA = *(float4*)&Bs[kk][tx * 4];
            float4 bB = *(float4*)&Bs[kk][64 + tx * 4];
            float a[8] = {aA.x, aA.y, aA.z, aA.w, aB.x, aB.y, aB.z, aB.w};
            float b[8] = {bA.x, bA.y, bA.z, bA.w, bB.x, bB.y, bB.z, bB.w};
            #pragma unroll
            for (int i = 0; i < 8; i++)
                #pragma unroll
                for (int j = 0; j < 8; j++) acc[i][j] += a[i] * b[j];
        }
    }
    // epilogue: thread owns rows m0+ty*8+i, cols {n0+tx*4..+3} and {n0+64+tx*4..+3}
    #pragma unroll
    for (int i = 0; i < 8; i++) {
        int r = m0 + ty * 8 + i;
        int b = r >> 12, l = r & 4095;
        int c0 = n0 + tx * 4;
        int h0 = c0 >> 6, d0 = c0 & 63;
        int c1 = c0 + 64;
        int h1 = c1 >> 6, d1 = c1 & 63;
        float* dst0 = Out + ((size_t)(b * 8 + h0) * 4096 + l) * 64 + d0;
        float* dst1 = Out + ((size_t)(b * 8 + h1) * 4096 + l) * 64 + d1;
        *(float4*)dst0 = make_float4(acc[i][0], acc[i][1], acc[i][2], acc[i][3]);
        *(float4*)dst1 = make_float4(acc[i][4], acc[i][5], acc[i][6], acc[i][7]);
    }
}

// ---------------- x -> bf16 --------------------------------------------------
__global__ __launch_bounds__(256) void convx_kernel(
    const float4* __restrict__ x4, ushort4* __restrict__ xb4)
{
    int i = blockIdx.x * 256 + threadIdx.x;   // 2,097,152
    float4 v = x4[i];
    ushort4 o;
    o.x = bf16r(v.x); o.y = bf16r(v.y); o.z = bf16r(v.z); o.w = bf16r(v.w);
    xb4[i] = o;
}

// ---------------- Wv -> WvT bf16 (transpose) ---------------------------------
__global__ __launch_bounds__(256) void convw_kernel(
    const float* __restrict__ Wv, unsigned short* __restrict__ WvT)
{
    __shared__ float t[32][33];
    int bx = blockIdx.x & 15, by = blockIdx.x >> 4;
    int tx = threadIdx.x & 31, ty = threadIdx.x >> 5;
    for (int i = ty; i < 32; i += 8) t[i][tx] = Wv[(size_t)(by * 32 + i) * 512 + bx * 32 + tx];
    __syncthreads();
    for (int i = ty; i < 32; i += 8)
        WvT[(size_t)(bx * 32 + i) * 512 + by * 32 + tx] = bf16r(t[tx][i]);
}

// ---------------- V GEMM via bf16 MFMA: A=x_bf16, B=WvT ------------------------
__global__ __launch_bounds__(256) void vgemm_kernel(
    const unsigned short* __restrict__ A,   // 16384 x 512 (row-major, bf16)
    const unsigned short* __restrict__ BT,  // 512(n) x 512(k) (row-major, bf16)
    float* __restrict__ V)
{
    int wave = threadIdx.x >> 6;
    int lane = threadIdx.x & 63;
    int m0 = blockIdx.x * 128 + (wave >> 1) * 64;
    int n0 = blockIdx.y * 128 + (wave & 1) * 64;
    int fr = lane & 15;          // non-K index within frag
    int kq = (lane >> 4) * 8;    // K offset within frag

    float4v acc[4][4];
    #pragma unroll
    for (int i = 0; i < 4; i++)
        #pragma unroll
        for (int j = 0; j < 4; j++) acc[i][j] = (float4v){0.f, 0.f, 0.f, 0.f};

    for (int k0 = 0; k0 < 512; k0 += 32) {
        short8 a[4], b[4];
        #pragma unroll
        for (int i = 0; i < 4; i++)
            a[i] = *(const short8*)(A + (size_t)(m0 + i * 16 + fr) * 512 + k0 + kq);
        #pragma unroll
        for (int j = 0; j < 4; j++)
            b[j] = *(const short8*)(BT + (size_t)(n0 + j * 16 + fr) * 512 + k0 + kq);
        #pragma unroll
        for (int i = 0; i < 4; i++)
            #pragma unroll
            for (int j = 0; j < 4; j++)
                acc[i][j] = __builtin_amdgcn_mfma_f32_16x16x32_bf16(a[i], b[j], acc[i][j], 0, 0, 0);
    }
    // C/D layout: col = lane&15, row = (lane>>4)*4 + reg   [m89/m91-verified]
    int rbase = (lane >> 4) * 4, ccol = lane & 15;
    #pragma unroll
    for (int i = 0; i < 4; i++)
        #pragma unroll
        for (int j = 0; j < 4; j++) {
            int c = n0 + j * 16 + ccol;
            int h = c >> 6, d = c & 63;
            #pragma unroll
            for (int r = 0; r < 4; r++) {
                int rg = m0 + i * 16 + rbase + r;
                int bb = rg >> 12, l = rg & 4095;
                V[((size_t)(bb * 8 + h) * 4096 + l) * 64 + d] = acc[i][j][r];
            }
        }
}

// ---------------- M = max_s(q.k_samp) - mean_s(q.k_samp), fp32 ----------------
__global__ __launch_bounds__(256) void m_kernel(
    const float* __restrict__ Q, const float* __restrict__ K,
    const int* __restrict__ idx, float* __restrict__ M)
{
    int inst = blockIdx.x * 4 + (threadIdx.x >> 6);   // bh*4096 + l
    int lane = threadIdx.x & 63;
    int g = lane >> 4;
    int t = lane & 15;
    int bh = inst >> 12;
    int l = inst & 4095;
    float4 qv = *(const float4*)(Q + (size_t)inst * 64 + t * 4);
    const float* kb = K + (size_t)bh * 4096 * 64;
    const int* irow = idx + (size_t)l * SS;
    float maxv = -1e30f, sum = 0.f;
    #pragma unroll
    for (int it = 0; it < 12; it++) {
        int s = it * 4 + g;
        bool valid = (s < SS);
        int j = irow[valid ? s : 0];
        float4 kv = *(const float4*)(kb + (size_t)j * 64 + t * 4);
        float p = qv.x * kv.x + qv.y * kv.y + qv.z * kv.z + qv.w * kv.w;
        p += __shfl_xor(p, 1, 64);
        p += __shfl_xor(p, 2, 64);
        p += __shfl_xor(p, 4, 64);
        p += __shfl_xor(p, 8, 64);
        if (valid) { maxv = fmaxf(maxv, p); sum += p; }
    }
    maxv = fmaxf(maxv, __shfl_xor(maxv, 16, 64));
    maxv = fmaxf(maxv, __shfl_xor(maxv, 32, 64));
    sum += __shfl_xor(sum, 16, 64);
    sum += __shfl_xor(sum, 32, 64);
    if (lane == 0) M[inst] = maxv - sum * (1.f / 45.f);
}

// ---------------- per-(b,h) top-45 of M over L ---------------------------------
__global__ __launch_bounds__(256) void topk_kernel(
    const float* __restrict__ M, int* __restrict__ tidx)
{
    int bh = blockIdx.x;
    __shared__ float vals[4096];
    __shared__ float rv[256];
    __shared__ int ri[256];
    int tid = threadIdx.x;
    for (int i = tid; i < 4096; i += 256) vals[i] = M[(size_t)bh * 4096 + i];
    __syncthreads();
    for (int it = 0; it < SS; it++) {
        float bv = -1e38f; int bi = 0;
        for (int i = tid; i < 4096; i += 256) {
            float v = vals[i];
            if (v > bv) { bv = v; bi = i; }
        }
        rv[tid] = bv; ri[tid] = bi;
        __syncthreads();
        for (int s = 128; s > 0; s >>= 1) {
            if (tid < s) {
                float v2 = rv[tid + s]; int i2 = ri[tid + s];
                if (v2 > rv[tid] || (v2 == rv[tid] && i2 < ri[tid])) { rv[tid] = v2; ri[tid] = i2; }
            }
            __syncthreads();
        }
        if (tid == 0) { tidx[bh * SS + it] = ri[0]; vals[ri[0]] = -1e38f; }
        __syncthreads();
    }
}

// ---------------- v mean partials over l-chunks --------------------------------
__global__ __launch_bounds__(256) void vmean_part_kernel(
    const float* __restrict__ V, float* __restrict__ vmp)
{
    int bh = blockIdx.x;
    int chunk = blockIdx.y;
    int d = threadIdx.x & 63, part = threadIdx.x >> 6;
    const float* vb = V + ((size_t)bh * 4096 + chunk * 256) * 64;
    float s = 0.f;
    for (int l = part; l < 256; l += 4) s += vb[(size_t)l * 64 + d];
    __shared__ float red[4][64];
    red[part][d] = s;
    __syncthreads();
    if (part == 0) vmp[((size_t)bh * 16 + chunk) * 64 + d] = red[0][d] + red[1][d] + red[2][d] + red[3][d];
}

// ---------------- vmean finalize + base_b = mean_row @ Wo ----------------------
__global__ __launch_bounds__(256) void base_kernel(
    const float* __restrict__ vmp, const float* __restrict__ Wo,
    float* __restrict__ vmean, float* __restrict__ base)
{
    int b = blockIdx.x;
    __shared__ float vmS[512];
    int tid = threadIdx.x;
    for (int i = tid; i < 512; i += 256) {
        int h = i >> 6, d = i & 63;
        float s = 0.f;
        #pragma unroll
        for (int c = 0; c < 16; c++) s += vmp[((size_t)(b * 8 + h) * 16 + c) * 64 + d];
        s *= (1.f / 4096.f);
        vmS[i] = s;
        vmean[(size_t)b * 512 + i] = s;
    }
    __syncthreads();
    for (int j = tid; j < 512; j += 256) {
        float s = 0.f;
        for (int i = 0; i < 512; i++) s += vmS[i] * Wo[(size_t)i * 512 + j];
        base[(size_t)b * 512 + j] = s;
    }
}

// ---------------- scores = Qr . k * scale ---------------------------------------
__global__ __launch_bounds__(256) void scores_kernel(
    const float* __restrict__ Q, const float* __restrict__ K,
    const int* __restrict__ tidx, float* __restrict__ attn)
{
    int ltile = blockIdx.x;
    int bh = blockIdx.y;
    __shared__ float Qs[48][68];
    __shared__ float Ks[64][68];
    __shared__ int tS[48];
    int tid = threadIdx.x;
    if (tid < 48) tS[tid] = (tid < SS) ? tidx[bh * SS + tid] : 0;
    __syncthreads();
    int lane = tid & 63, w = tid >> 6;
    for (int u = w; u < 48; u += 4)
        Qs[u][lane] = Q[((size_t)bh * 4096 + tS[u]) * 64 + lane];
    for (int r = w; r < 64; r += 4)
        Ks[r][lane] = K[((size_t)bh * 4096 + ltile * 64 + r) * 64 + lane];
    __syncthreads();
    if (tid < 192) {
        int ug = tid >> 4, lg = tid & 15;
        float acc[4][4];
        #pragma unroll
        for (int i = 0; i < 4; i++)
            #pragma unroll
            for (int j = 0; j < 4; j++) acc[i][j] = 0.f;
        for (int d0 = 0; d0 < 64; d0 += 4) {
            float4 a[4], b[4];
            #pragma unroll
            for (int i = 0; i < 4; i++) a[i] = *(float4*)&Qs[ug * 4 + i][d0];
            #pragma unroll
            for (int j = 0; j < 4; j++) b[j] = *(float4*)&Ks[lg * 4 + j][d0];
            #pragma unroll
            for (int i = 0; i < 4; i++)
                #pragma unroll
                for (int j = 0; j < 4; j++)
                    acc[i][j] += a[i].x * b[j].x + a[i].y * b[j].y + a[i].z * b[j].z + a[i].w * b[j].w;
        }
        const float scale = 0.125f;
        #pragma unroll
        for (int i = 0; i < 4; i++) {
            int u = ug * 4 + i;
            if (u < SS) {
                float4 r = make_float4(acc[i][0] * scale, acc[i][1] * scale,
                                       acc[i][2] * scale, acc[i][3] * scale);
                *(float4*)(attn + (size_t)(bh * SS + u) * 4096 + ltile * 64 + lg * 4) = r;
            }
        }
    }
}

// ---------------- softmax over L per (bh,u) row --------------------------------
__global__ __launch_bounds__(256) void softmax_kernel(float* __restrict__ attn)
{
    int rr = blockIdx.x;
    float* row = attn + (size_t)rr * 4096;
    int tid = threadIdx.x;
    float v[16];
    float m = -1e30f;
    #pragma unroll
    for (int i = 0; i < 16; i++) { v[i] = row[tid + 256 * i]; m = fmaxf(m, v[i]); }
    __shared__ float red[256];
    red[tid] = m; __syncthreads();
    for (int s = 128; s > 0; s >>= 1) { if (tid < s) red[tid] = fmaxf(red[tid], red[tid + s]); __syncthreads(); }
    m = red[0]; __syncthreads();
    float sum = 0.f;
    #pragma unroll
    for (int i = 0; i < 16; i++) { v[i] = __expf(v[i] - m); sum += v[i]; }
    red[tid] = sum; __syncthreads();
    for (int s = 128; s > 0; s >>= 1) { if (tid < s) red[tid] += red[tid + s]; __syncthreads(); }
    float inv = 1.f / red[0];
    #pragma unroll
    for (int i = 0; i < 16; i++) row[tid + 256 * i] = v[i] * inv;
}

// ---------------- PV partials ---------------------------------------------------
__global__ __launch_bounds__(256) void pv_kernel(
    const float* __restrict__ attn, const float* __restrict__ V,
    float* __restrict__ part)
{
    int bh = blockIdx.x;
    int ks = blockIdx.y;
    int tid = threadIdx.x;
    int d = tid & 63, w = tid >> 6;
    float acc[12];
    #pragma unroll
    for (int j = 0; j < 12; j++) acc[j] = 0.f;
    const float* vb = V + ((size_t)bh * 4096 + ks * 256) * 64;
    for (int li = 0; li < 256; li++) {
        float vv = vb[(size_t)li * 64 + d];
        #pragma unroll
        for (int j = 0; j < 12; j++) {
            int u = w + 4 * j;
            float a = (u < SS) ? attn[(size_t)(bh * SS + u) * 4096 + ks * 256 + li] : 0.f;
            acc[j] += a * vv;
        }
    }
    #pragma unroll
    for (int j = 0; j < 12; j++) {
        int u = w + 4 * j;
        if (u < SS) part[(((size_t)bh * 16 + ks) * SS + u) * 64 + d] = acc[j];
    }
}

// ---------------- delta_out[bh,u,:] = (ctx_sel - vmean) @ Wo_h ------------------
__global__ __launch_bounds__(256) void delta_kernel(
    const float* __restrict__ part, const float* __restrict__ vmean,
    const float* __restrict__ Wo, float* __restrict__ dout)
{
    int rr = blockIdx.x;
    int bh = rr / SS, u = rr % SS;
    int h = bh & 7;
    __shared__ float dS[64];
    int tid = threadIdx.x;
    if (tid < 64) {
        float s = 0.f;
        #pragma unroll
        for (int c = 0; c < 16; c++) s += part[(((size_t)bh * 16 + c) * SS + u) * 64 + tid];
        dS[tid] = s - vmean[(size_t)bh * 64 + tid];
    }
    __syncthreads();
    for (int j = tid; j < 512; j += 256) {
        float s = 0.f;
        #pragma unroll
        for (int dd = 0; dd < 64; dd++) s += dS[dd] * Wo[(size_t)(h * 64 + dd) * 512 + j];
        dout[(size_t)rr * 512 + j] = s;
    }
}

// ---------------- fill out with per-b base row ---------------------------------
__global__ __launch_bounds__(256) void fill_kernel(
    const float4* __restrict__ base4, float4* __restrict__ out4)
{
    int i = blockIdx.x * 256 + threadIdx.x;
    int b = i >> 19;
    int j4 = i & 127;
    out4[i] = base4[b * 128 + j4];
}

// ---------------- scatter-add deltas into selected rows -------------------------
__global__ __launch_bounds__(256) void scatter_kernel(
    const float* __restrict__ dout, const int* __restrict__ tidx,
    float* __restrict__ out)
{
    int rr = blockIdx.x;
    int bh = rr / SS;
    int b = bh >> 3;
    int l = tidx[rr];
    float* orow = out + ((size_t)b * 4096 + l) * 512;
    const float* drow = dout + (size_t)rr * 512;
    for (int j = threadIdx.x; j < 512; j += 256)
        atomicAdd(orow + j, drow[j]);
}

extern "C" void kernel_launch(void* const* d_in, const int* in_sizes, int n_in,
                              void* d_out, int out_size, void* d_ws, size_t ws_size,
                              hipStream_t stream)
{
    const float* x  = (const float*)d_in[0];
    const float* Wq = (const float*)d_in[1];
    const float* Wk = (const float*)d_in[2];
    const float* Wv = (const float*)d_in[3];
    const float* Wo = (const float*)d_in[4];
    const int*  idx = (const int*)d_in[5];
    float* out = (float*)d_out;

    float* W = (float*)d_ws;
    float* Q     = W;                    // 8,388,608
    float* K     = W + 8388608;          // 8,388,608
    float* V     = W + 16777216;         // 8,388,608
    float* Mv    = W + 25165824;         // 131,072
    float* attn  = W + 25296896;         // 5,898,240
    float* part  = W + 31195136;         // 1,474,560
    float* dout  = W + 32669696;         // 737,280
    float* vmp   = W + 33406976;         // 32,768
    float* vmean = W + 33439744;         // 2,048
    float* base  = W + 33441792;         // 2,048
    int*   tidx  = (int*)(W + 33443840); // 1,440 ints

    // bf16 staging buffers alias the attn region (dead until scores_kernel)
    unsigned short* xb  = (unsigned short*)(W + 25296896);            // 8,388,608 u16
    unsigned short* wvt = (unsigned short*)(W + 25296896 + 4194304);  // 262,144 u16

    convx_kernel<<<8192, 256, 0, stream>>>((const float4*)x, (ushort4*)xb);
    convw_kernel<<<256, 256, 0, stream>>>(Wv, wvt);
    qk_gemm_kernel<<<dim3(128, 4, 2), 256, 0, stream>>>(x, Wq, Wk, Q, K);
    vgemm_kernel<<<dim3(128, 4), 256, 0, stream>>>(xb, wvt, V);
    m_kernel<<<32768, 256, 0, stream>>>(Q, K, idx, Mv);
    topk_kernel<<<32, 256, 0, stream>>>(Mv, tidx);
    vmean_part_kernel<<<dim3(32, 16), 256, 0, stream>>>(V, vmp);
    base_kernel<<<4, 256, 0, stream>>>(vmp, Wo, vmean, base);
    scores_kernel<<<dim3(64, 32), 256, 0, stream>>>(Q, K, tidx, attn);
    softmax_kernel<<<1440, 256, 0, stream>>>(attn);
    pv_kernel<<<dim3(32, 16), 256, 0, stream>>>(attn, V, part);
    delta_kernel<<<1440, 256, 0, stream>>>(part, vmean, Wo, dout);
    fill_kernel<<<8192, 256, 0, stream>>>((const float4*)base, (float4*)out);
    scatter_kernel<<<1440, 256, 0, stream>>>(dout, tidx, out);
}

// Round 4
// 616.336 us; speedup vs baseline: 1.6798x; 1.1370x over previous
//
#include <hip/hip_runtime.h>
#include <cmath>

#define L_SEQ 4096
#define NH 8
#define DH 64
#define SS 45

typedef __attribute__((ext_vector_type(8))) short short8;
typedef __attribute__((ext_vector_type(4))) float float4v;

__device__ inline unsigned short bf16r(float f) {
    unsigned int u = __float_as_uint(f);
    unsigned int r = (u + 0x7fff + ((u >> 16) & 1)) >> 16;
    return (unsigned short)r;
}

// ---- Wq/Wk/Wv -> transposed bf16 hi/lo: WT[z][n][k], z in {0:q,1:k,2:v} -------
__global__ __launch_bounds__(256) void convw2_kernel(
    const float* __restrict__ Wq, const float* __restrict__ Wk, const float* __restrict__ Wv,
    unsigned short* __restrict__ WTh, unsigned short* __restrict__ WTl)
{
    const float* W = (blockIdx.y == 0) ? Wq : (blockIdx.y == 1) ? Wk : Wv;
    unsigned short* th = WTh + (size_t)blockIdx.y * 512 * 512;
    unsigned short* tl = WTl + (size_t)blockIdx.y * 512 * 512;
    __shared__ float t[32][33];
    int bx = blockIdx.x & 15, by = blockIdx.x >> 4;
    int tx = threadIdx.x & 31, ty = threadIdx.x >> 5;
    for (int i = ty; i < 32; i += 8) t[i][tx] = W[(size_t)(by * 32 + i) * 512 + bx * 32 + tx];
    __syncthreads();
    for (int i = ty; i < 32; i += 8) {
        float f = t[tx][i];   // W[k = by*32+tx][n = bx*32+i]
        unsigned short h = bf16r(f);
        float fh = __uint_as_float((unsigned)h << 16);
        unsigned short lo = bf16r(f - fh);
        th[(size_t)(bx * 32 + i) * 512 + by * 32 + tx] = h;
        tl[(size_t)(bx * 32 + i) * 512 + by * 32 + tx] = lo;
    }
}

// ---- fused Q,K projection via split-bf16 MFMA (hi*hi + hi*lo + lo*hi) ---------
__global__ __launch_bounds__(256, 2) void qk2_kernel(
    const float* __restrict__ X,
    const unsigned short* __restrict__ WTh, const unsigned short* __restrict__ WTl,
    float* __restrict__ Q, float* __restrict__ K)
{
    int wave = threadIdx.x >> 6;
    int lane = threadIdx.x & 63;
    int m0 = blockIdx.x * 128 + (wave >> 1) * 64;
    int n0 = blockIdx.y * 128 + (wave & 1) * 64;
    int fr = lane & 15;
    int kq = (lane >> 4) * 8;
    const unsigned short* Bqh = WTh;
    const unsigned short* Bql = WTl;
    const unsigned short* Bkh = WTh + 512 * 512;
    const unsigned short* Bkl = WTl + 512 * 512;

    float4v accq[4][4], acck[4][4];
    #pragma unroll
    for (int i = 0; i < 4; i++)
        #pragma unroll
        for (int j = 0; j < 4; j++) {
            accq[i][j] = (float4v){0.f, 0.f, 0.f, 0.f};
            acck[i][j] = (float4v){0.f, 0.f, 0.f, 0.f};
        }

    for (int k0 = 0; k0 < 512; k0 += 32) {
        short8 ah[4], al[4];
        #pragma unroll
        for (int i = 0; i < 4; i++) {
            const float* ap = X + (size_t)(m0 + i * 16 + fr) * 512 + k0 + kq;
            float4 f0 = *(const float4*)ap;
            float4 f1 = *(const float4*)(ap + 4);
            float fv[8] = {f0.x, f0.y, f0.z, f0.w, f1.x, f1.y, f1.z, f1.w};
            short8 h, l;
            #pragma unroll
            for (int e = 0; e < 8; e++) {
                unsigned short hh = bf16r(fv[e]);
                h[e] = (short)hh;
                float fh = __uint_as_float((unsigned)hh << 16);
                l[e] = (short)bf16r(fv[e] - fh);
            }
            ah[i] = h; al[i] = l;
        }
        #pragma unroll
        for (int j = 0; j < 4; j++) {
            size_t boff = (size_t)(n0 + j * 16 + fr) * 512 + k0 + kq;
            short8 bqh = *(const short8*)(Bqh + boff);
            short8 bql = *(const short8*)(Bql + boff);
            short8 bkh = *(const short8*)(Bkh + boff);
            short8 bkl = *(const short8*)(Bkl + boff);
            #pragma unroll
            for (int i = 0; i < 4; i++) {
                accq[i][j] = __builtin_amdgcn_mfma_f32_16x16x32_bf16(ah[i], bqh, accq[i][j], 0, 0, 0);
                accq[i][j] = __builtin_amdgcn_mfma_f32_16x16x32_bf16(ah[i], bql, accq[i][j], 0, 0, 0);
                accq[i][j] = __builtin_amdgcn_mfma_f32_16x16x32_bf16(al[i], bqh, accq[i][j], 0, 0, 0);
                acck[i][j] = __builtin_amdgcn_mfma_f32_16x16x32_bf16(ah[i], bkh, acck[i][j], 0, 0, 0);
                acck[i][j] = __builtin_amdgcn_mfma_f32_16x16x32_bf16(ah[i], bkl, acck[i][j], 0, 0, 0);
                acck[i][j] = __builtin_amdgcn_mfma_f32_16x16x32_bf16(al[i], bkh, acck[i][j], 0, 0, 0);
            }
        }
    }
    // C/D layout: col = lane&15, row = (lane>>4)*4 + reg   [m89/m91-verified]
    int rbase = (lane >> 4) * 4, ccol = lane & 15;
    #pragma unroll
    for (int i = 0; i < 4; i++)
        #pragma unroll
        for (int j = 0; j < 4; j++) {
            int c = n0 + j * 16 + ccol;
            int h = c >> 6, d = c & 63;
            #pragma unroll
            for (int r = 0; r < 4; r++) {
                int rg = m0 + i * 16 + rbase + r;
                int bb = rg >> 12, l = rg & 4095;
                size_t off = ((size_t)(bb * 8 + h) * 4096 + l) * 64 + d;
                Q[off] = accq[i][j][r];
                K[off] = acck[i][j][r];
            }
        }
}

// ---- V GEMM via bf16 MFMA, A converted from fp32 in-register ------------------
__global__ __launch_bounds__(256) void vgemm_kernel(
    const float* __restrict__ X,
    const unsigned short* __restrict__ BTh,   // WT z=2 (hi)
    float* __restrict__ V)
{
    int wave = threadIdx.x >> 6;
    int lane = threadIdx.x & 63;
    int m0 = blockIdx.x * 128 + (wave >> 1) * 64;
    int n0 = blockIdx.y * 128 + (wave & 1) * 64;
    int fr = lane & 15;
    int kq = (lane >> 4) * 8;

    float4v acc[4][4];
    #pragma unroll
    for (int i = 0; i < 4; i++)
        #pragma unroll
        for (int j = 0; j < 4; j++) acc[i][j] = (float4v){0.f, 0.f, 0.f, 0.f};

    for (int k0 = 0; k0 < 512; k0 += 32) {
        short8 a[4], b[4];
        #pragma unroll
        for (int i = 0; i < 4; i++) {
            const float* ap = X + (size_t)(m0 + i * 16 + fr) * 512 + k0 + kq;
            float4 f0 = *(const float4*)ap;
            float4 f1 = *(const float4*)(ap + 4);
            float fv[8] = {f0.x, f0.y, f0.z, f0.w, f1.x, f1.y, f1.z, f1.w};
            short8 h;
            #pragma unroll
            for (int e = 0; e < 8; e++) h[e] = (short)bf16r(fv[e]);
            a[i] = h;
        }
        #pragma unroll
        for (int j = 0; j < 4; j++)
            b[j] = *(const short8*)(BTh + (size_t)(n0 + j * 16 + fr) * 512 + k0 + kq);
        #pragma unroll
        for (int i = 0; i < 4; i++)
            #pragma unroll
            for (int j = 0; j < 4; j++)
                acc[i][j] = __builtin_amdgcn_mfma_f32_16x16x32_bf16(a[i], b[j], acc[i][j], 0, 0, 0);
    }
    int rbase = (lane >> 4) * 4, ccol = lane & 15;
    #pragma unroll
    for (int i = 0; i < 4; i++)
        #pragma unroll
        for (int j = 0; j < 4; j++) {
            int c = n0 + j * 16 + ccol;
            int h = c >> 6, d = c & 63;
            #pragma unroll
            for (int r = 0; r < 4; r++) {
                int rg = m0 + i * 16 + rbase + r;
                int bb = rg >> 12, l = rg & 4095;
                V[((size_t)(bb * 8 + h) * 4096 + l) * 64 + d] = acc[i][j][r];
            }
        }
}

// ---------------- M = max_s(q.k_samp) - mean_s(q.k_samp), fp32 ----------------
__global__ __launch_bounds__(256) void m_kernel(
    const float* __restrict__ Q, const float* __restrict__ K,
    const int* __restrict__ idx, float* __restrict__ M)
{
    int inst = blockIdx.x * 4 + (threadIdx.x >> 6);   // bh*4096 + l
    int lane = threadIdx.x & 63;
    int g = lane >> 4;
    int t = lane & 15;
    int bh = inst >> 12;
    int l = inst & 4095;
    float4 qv = *(const float4*)(Q + (size_t)inst * 64 + t * 4);
    const float* kb = K + (size_t)bh * 4096 * 64;
    const int* irow = idx + (size_t)l * SS;
    float maxv = -1e30f, sum = 0.f;
    #pragma unroll
    for (int it = 0; it < 12; it++) {
        int s = it * 4 + g;
        bool valid = (s < SS);
        int j = irow[valid ? s : 0];
        float4 kv = *(const float4*)(kb + (size_t)j * 64 + t * 4);
        float p = qv.x * kv.x + qv.y * kv.y + qv.z * kv.z + qv.w * kv.w;
        p += __shfl_xor(p, 1, 64);
        p += __shfl_xor(p, 2, 64);
        p += __shfl_xor(p, 4, 64);
        p += __shfl_xor(p, 8, 64);
        if (valid) { maxv = fmaxf(maxv, p); sum += p; }
    }
    maxv = fmaxf(maxv, __shfl_xor(maxv, 16, 64));
    maxv = fmaxf(maxv, __shfl_xor(maxv, 32, 64));
    sum += __shfl_xor(sum, 16, 64);
    sum += __shfl_xor(sum, 32, 64);
    if (lane == 0) M[inst] = maxv - sum * (1.f / 45.f);
}

// ---------------- per-(b,h) top-45 of M over L (wave-shuffle reduce) -----------
__global__ __launch_bounds__(256) void topk_kernel(
    const float* __restrict__ M, int* __restrict__ tidx)
{
    int bh = blockIdx.x;
    __shared__ float vals[4096];
    __shared__ float wv[4];
    __shared__ int wi[4];
    int tid = threadIdx.x;
    int lane = tid & 63, w = tid >> 6;
    for (int i = tid; i < 4096; i += 256) vals[i] = M[(size_t)bh * 4096 + i];
    __syncthreads();
    for (int it = 0; it < SS; it++) {
        float bv = -1e38f; int bi = 0x7fffffff;
        for (int i = tid; i < 4096; i += 256) {
            float v = vals[i];
            if (v > bv) { bv = v; bi = i; }
        }
        #pragma unroll
        for (int s = 32; s > 0; s >>= 1) {
            float v2 = __shfl_xor(bv, s, 64);
            int i2 = __shfl_xor(bi, s, 64);
            if (v2 > bv || (v2 == bv && i2 < bi)) { bv = v2; bi = i2; }
        }
        if (lane == 0) { wv[w] = bv; wi[w] = bi; }
        __syncthreads();
        if (tid == 0) {
            float b0 = wv[0]; int i0 = wi[0];
            #pragma unroll
            for (int k = 1; k < 4; k++)
                if (wv[k] > b0 || (wv[k] == b0 && wi[k] < i0)) { b0 = wv[k]; i0 = wi[k]; }
            tidx[bh * SS + it] = i0;
            vals[i0] = -1e38f;
        }
        __syncthreads();
    }
}

// ---------------- v mean partials over l-chunks --------------------------------
__global__ __launch_bounds__(256) void vmean_part_kernel(
    const float* __restrict__ V, float* __restrict__ vmp)
{
    int bh = blockIdx.x;
    int chunk = blockIdx.y;
    int d = threadIdx.x & 63, part = threadIdx.x >> 6;
    const float* vb = V + ((size_t)bh * 4096 + chunk * 256) * 64;
    float s = 0.f;
    for (int l = part; l < 256; l += 4) s += vb[(size_t)l * 64 + d];
    __shared__ float red[4][64];
    red[part][d] = s;
    __syncthreads();
    if (part == 0) vmp[((size_t)bh * 16 + chunk) * 64 + d] = red[0][d] + red[1][d] + red[2][d] + red[3][d];
}

// ---------------- vmean finalize + base_b = mean_row @ Wo ----------------------
__global__ __launch_bounds__(256) void base_kernel(
    const float* __restrict__ vmp, const float* __restrict__ Wo,
    float* __restrict__ vmean, float* __restrict__ base)
{
    int b = blockIdx.x;
    __shared__ float vmS[512];
    int tid = threadIdx.x;
    for (int i = tid; i < 512; i += 256) {
        int h = i >> 6, d = i & 63;
        float s = 0.f;
        #pragma unroll
        for (int c = 0; c < 16; c++) s += vmp[((size_t)(b * 8 + h) * 16 + c) * 64 + d];
        s *= (1.f / 4096.f);
        vmS[i] = s;
        vmean[(size_t)b * 512 + i] = s;
    }
    __syncthreads();
    for (int j = tid; j < 512; j += 256) {
        float s = 0.f;
        for (int i = 0; i < 512; i++) s += vmS[i] * Wo[(size_t)i * 512 + j];
        base[(size_t)b * 512 + j] = s;
    }
}

// ---------------- scores = Qr . k * scale ---------------------------------------
__global__ __launch_bounds__(256) void scores_kernel(
    const float* __restrict__ Q, const float* __restrict__ K,
    const int* __restrict__ tidx, float* __restrict__ attn)
{
    int ltile = blockIdx.x;
    int bh = blockIdx.y;
    __shared__ float Qs[48][68];
    __shared__ float Ks[64][68];
    __shared__ int tS[48];
    int tid = threadIdx.x;
    if (tid < 48) tS[tid] = (tid < SS) ? tidx[bh * SS + tid] : 0;
    __syncthreads();
    int lane = tid & 63, w = tid >> 6;
    for (int u = w; u < 48; u += 4)
        Qs[u][lane] = Q[((size_t)bh * 4096 + tS[u]) * 64 + lane];
    for (int r = w; r < 64; r += 4)
        Ks[r][lane] = K[((size_t)bh * 4096 + ltile * 64 + r) * 64 + lane];
    __syncthreads();
    if (tid < 192) {
        int ug = tid >> 4, lg = tid & 15;
        float acc[4][4];
        #pragma unroll
        for (int i = 0; i < 4; i++)
            #pragma unroll
            for (int j = 0; j < 4; j++) acc[i][j] = 0.f;
        for (int d0 = 0; d0 < 64; d0 += 4) {
            float4 a[4], b[4];
            #pragma unroll
            for (int i = 0; i < 4; i++) a[i] = *(float4*)&Qs[ug * 4 + i][d0];
            #pragma unroll
            for (int j = 0; j < 4; j++) b[j] = *(float4*)&Ks[lg * 4 + j][d0];
            #pragma unroll
            for (int i = 0; i < 4; i++)
                #pragma unroll
                for (int j = 0; j < 4; j++)
                    acc[i][j] += a[i].x * b[j].x + a[i].y * b[j].y + a[i].z * b[j].z + a[i].w * b[j].w;
        }
        const float scale = 0.125f;
        #pragma unroll
        for (int i = 0; i < 4; i++) {
            int u = ug * 4 + i;
            if (u < SS) {
                float4 r = make_float4(acc[i][0] * scale, acc[i][1] * scale,
                                       acc[i][2] * scale, acc[i][3] * scale);
                *(float4*)(attn + (size_t)(bh * SS + u) * 4096 + ltile * 64 + lg * 4) = r;
            }
        }
    }
}

// ---------------- softmax over L per (bh,u) row --------------------------------
__global__ __launch_bounds__(256) void softmax_kernel(float* __restrict__ attn)
{
    int rr = blockIdx.x;
    float* row = attn + (size_t)rr * 4096;
    int tid = threadIdx.x;
    float v[16];
    float m = -1e30f;
    #pragma unroll
    for (int i = 0; i < 16; i++) { v[i] = row[tid + 256 * i]; m = fmaxf(m, v[i]); }
    __shared__ float red[256];
    red[tid] = m; __syncthreads();
    for (int s = 128; s > 0; s >>= 1) { if (tid < s) red[tid] = fmaxf(red[tid], red[tid + s]); __syncthreads(); }
    m = red[0]; __syncthreads();
    float sum = 0.f;
    #pragma unroll
    for (int i = 0; i < 16; i++) { v[i] = __expf(v[i] - m); sum += v[i]; }
    red[tid] = sum; __syncthreads();
    for (int s = 128; s > 0; s >>= 1) { if (tid < s) red[tid] += red[tid + s]; __syncthreads(); }
    float inv = 1.f / red[0];
    #pragma unroll
    for (int i = 0; i < 16; i++) row[tid + 256 * i] = v[i] * inv;
}

// ---------------- PV partials ---------------------------------------------------
__global__ __launch_bounds__(256) void pv_kernel(
    const float* __restrict__ attn, const float* __restrict__ V,
    float* __restrict__ part)
{
    int bh = blockIdx.x;
    int ks = blockIdx.y;
    int tid = threadIdx.x;
    int d = tid & 63, w = tid >> 6;
    float acc[12];
    #pragma unroll
    for (int j = 0; j < 12; j++) acc[j] = 0.f;
    const float* vb = V + ((size_t)bh * 4096 + ks * 256) * 64;
    for (int li = 0; li < 256; li++) {
        float vv = vb[(size_t)li * 64 + d];
        #pragma unroll
        for (int j = 0; j < 12; j++) {
            int u = w + 4 * j;
            float a = (u < SS) ? attn[(size_t)(bh * SS + u) * 4096 + ks * 256 + li] : 0.f;
            acc[j] += a * vv;
        }
    }
    #pragma unroll
    for (int j = 0; j < 12; j++) {
        int u = w + 4 * j;
        if (u < SS) part[(((size_t)bh * 16 + ks) * SS + u) * 64 + d] = acc[j];
    }
}

// ---------------- delta_out[bh,u,:] = (ctx_sel - vmean) @ Wo_h ------------------
__global__ __launch_bounds__(256) void delta_kernel(
    const float* __restrict__ part, const float* __restrict__ vmean,
    const float* __restrict__ Wo, float* __restrict__ dout)
{
    int rr = blockIdx.x;
    int bh = rr / SS, u = rr % SS;
    int h = bh & 7;
    __shared__ float dS[64];
    int tid = threadIdx.x;
    if (tid < 64) {
        float s = 0.f;
        #pragma unroll
        for (int c = 0; c < 16; c++) s += part[(((size_t)bh * 16 + c) * SS + u) * 64 + tid];
        dS[tid] = s - vmean[(size_t)bh * 64 + tid];
    }
    __syncthreads();
    for (int j = tid; j < 512; j += 256) {
        float s = 0.f;
        #pragma unroll
        for (int dd = 0; dd < 64; dd++) s += dS[dd] * Wo[(size_t)(h * 64 + dd) * 512 + j];
        dout[(size_t)rr * 512 + j] = s;
    }
}

// ---------------- fill out with per-b base row ---------------------------------
__global__ __launch_bounds__(256) void fill_kernel(
    const float4* __restrict__ base4, float4* __restrict__ out4)
{
    int i = blockIdx.x * 256 + threadIdx.x;
    int b = i >> 19;
    int j4 = i & 127;
    out4[i] = base4[b * 128 + j4];
}

// ---------------- scatter-add deltas into selected rows -------------------------
__global__ __launch_bounds__(256) void scatter_kernel(
    const float* __restrict__ dout, const int* __restrict__ tidx,
    float* __restrict__ out)
{
    int rr = blockIdx.x;
    int bh = rr / SS;
    int b = bh >> 3;
    int l = tidx[rr];
    float* orow = out + ((size_t)b * 4096 + l) * 512;
    const float* drow = dout + (size_t)rr * 512;
    for (int j = threadIdx.x; j < 512; j += 256)
        atomicAdd(orow + j, drow[j]);
}

extern "C" void kernel_launch(void* const* d_in, const int* in_sizes, int n_in,
                              void* d_out, int out_size, void* d_ws, size_t ws_size,
                              hipStream_t stream)
{
    const float* x  = (const float*)d_in[0];
    const float* Wq = (const float*)d_in[1];
    const float* Wk = (const float*)d_in[2];
    const float* Wv = (const float*)d_in[3];
    const float* Wo = (const float*)d_in[4];
    const int*  idx = (const int*)d_in[5];
    float* out = (float*)d_out;

    float* W = (float*)d_ws;
    float* Q     = W;                    // 8,388,608
    float* K     = W + 8388608;          // 8,388,608
    float* V     = W + 16777216;         // 8,388,608
    float* Mv    = W + 25165824;         // 131,072
    float* attn  = W + 25296896;         // 5,898,240
    float* part  = W + 31195136;         // 1,474,560
    float* dout  = W + 32669696;         // 737,280
    float* vmp   = W + 33406976;         // 32,768
    float* vmean = W + 33439744;         // 2,048
    float* base  = W + 33441792;         // 2,048
    int*   tidx  = (int*)(W + 33443840); // 1,440 ints

    // weight staging (bf16 hi/lo transposed, 3x512x512 each) aliases `part`
    // (dead until pv_kernel; qk2/vgemm consume it long before)
    unsigned short* WTh = (unsigned short*)(W + 31195136);            // 786,432 u16
    unsigned short* WTl = (unsigned short*)(W + 31195136 + 393216);   // 786,432 u16

    convw2_kernel<<<dim3(256, 3), 256, 0, stream>>>(Wq, Wk, Wv, WTh, WTl);
    qk2_kernel<<<dim3(128, 4), 256, 0, stream>>>(x, WTh, WTl, Q, K);
    vgemm_kernel<<<dim3(128, 4), 256, 0, stream>>>(x, WTh + (size_t)2 * 512 * 512, V);
    m_kernel<<<32768, 256, 0, stream>>>(Q, K, idx, Mv);
    topk_kernel<<<32, 256, 0, stream>>>(Mv, tidx);
    vmean_part_kernel<<<dim3(32, 16), 256, 0, stream>>>(V, vmp);
    base_kernel<<<4, 256, 0, stream>>>(vmp, Wo, vmean, base);
    scores_kernel<<<dim3(64, 32), 256, 0, stream>>>(Q, K, tidx, attn);
    softmax_kernel<<<1440, 256, 0, stream>>>(attn);
    pv_kernel<<<dim3(32, 16), 256, 0, stream>>>(attn, V, part);
    delta_kernel<<<1440, 256, 0, stream>>>(part, vmean, Wo, dout);
    fill_kernel<<<8192, 256, 0, stream>>>((const float4*)base, (float4*)out);
    scatter_kernel<<<1440, 256, 0, stream>>>(dout, tidx, out);
}